// Round 6
// baseline (1770.164 us; speedup 1.0000x reference)
//
#include <hip/hip_runtime.h>
#include <hip/hip_bf16.h>
#include <stdint.h>

// ---------------------------------------------------------------------------
// LinearQuantizer: y = fakequant_i8(x, per-tensor) @ fakequant_i8(W, per-row)^T + b
// int8 GEMM via v_mfma_i32_16x16x64_i8. 256x512 tile, BK=64, 3 LDS buffers,
// 2-phase/K-tile single-barrier schedule (T2 swizzle + counted vmcnt + T5
// setprio + drift-by-one). Per-wave output 128x128 (acc[8][8]) -> MFMA-bound.
// ---------------------------------------------------------------------------

#define QMAX_F 127.0f
#define EPS_F 1e-8f

typedef int v4i __attribute__((ext_vector_type(4)));

static constexpr size_t WSCALE_OFF = 64;
static constexpr size_t XQ_OFF = 1u << 16;

__device__ __forceinline__ int quant1m(float v, float rs) {
    float t = v * rs;
    t = fminf(fmaxf(t, -QMAX_F), QMAX_F);
    return (int)rintf(t);
}

// ---------------- prep: x-absmax (atomicMax) + per-row W quant ----------------
__global__ void prep_kernel(const float4* __restrict__ x, int nx4,
                            const float4* __restrict__ w, int* __restrict__ wq,
                            float* __restrict__ w_scale, int K4,
                            unsigned* __restrict__ amax) {
    const int t = threadIdx.x;  // 256
    const int row = blockIdx.x;

    float xm = 0.0f;
    for (int i = blockIdx.x * 256 + t; i < nx4; i += gridDim.x * 256) {
        float4 v = x[i];
        xm = fmaxf(xm, fmaxf(fmaxf(fabsf(v.x), fabsf(v.y)), fmaxf(fabsf(v.z), fabsf(v.w))));
    }

    const float4* wr = w + (size_t)row * K4;
    float4 vals[4];
    float wm = 0.0f;
    for (int i = 0; i < 4; i++) {
        float4 v = wr[t + 256 * i];
        vals[i] = v;
        wm = fmaxf(wm, fmaxf(fmaxf(fabsf(v.x), fabsf(v.y)), fmaxf(fabsf(v.z), fabsf(v.w))));
    }

    for (int off = 32; off > 0; off >>= 1) {
        xm = fmaxf(xm, __shfl_xor(xm, off));
        wm = fmaxf(wm, __shfl_xor(wm, off));
    }
    __shared__ float sx[4], sw[4];
    if ((t & 63) == 0) { sx[t >> 6] = xm; sw[t >> 6] = wm; }
    __syncthreads();
    float xb = fmaxf(fmaxf(sx[0], sx[1]), fmaxf(sx[2], sx[3]));
    float wb = fmaxf(fmaxf(sw[0], sw[1]), fmaxf(sw[2], sw[3]));
    if (t == 0) atomicMax(amax, __float_as_uint(xb));

    float s = fmaxf(wb / QMAX_F, EPS_F);
    if (t == 0) w_scale[row] = s;
    float rs = 1.0f / s;
    int* wqr = wq + (size_t)row * K4;
    for (int i = 0; i < 4; i++) {
        float4 v = vals[i];
        int q0 = quant1m(v.x, rs), q1 = quant1m(v.y, rs), q2 = quant1m(v.z, rs), q3 = quant1m(v.w, rs);
        wqr[t + 256 * i] = (q0 & 0xff) | ((q1 & 0xff) << 8) | ((q2 & 0xff) << 16) | ((q3 & 0xff) << 24);
    }
}

// ---------------- quantize x -> int8 ----------------
__global__ void quantx_kernel(const float4* __restrict__ x, const unsigned* __restrict__ amax,
                              int* __restrict__ xq, int n4) {
    float s = fmaxf(__uint_as_float(*amax) / QMAX_F, EPS_F);
    float rs = 1.0f / s;
    int tid = blockIdx.x * blockDim.x + threadIdx.x;
    int stride = gridDim.x * blockDim.x;
    for (int i = tid; i < n4; i += stride) {
        float4 v = x[i];
        int q0 = quant1m(v.x, rs), q1 = quant1m(v.y, rs), q2 = quant1m(v.z, rs), q3 = quant1m(v.w, rs);
        xq[i] = (q0 & 0xff) | ((q1 & 0xff) << 8) | ((q2 & 0xff) << 16) | ((q3 & 0xff) << 24);
    }
}

// ---------------- int8 GEMM: 256x512 tile, BK=64, 3-buffer 2-phase ----------
#define BM 256
#define BN 512
#define BKB 64

static constexpr unsigned BUF_SZ = 49152;  // A 16KB + B 32KB per buffer

__device__ __forceinline__ void gload16(const char* g, char* l) {
    __builtin_amdgcn_global_load_lds(
        (const __attribute__((address_space(1))) void*)g,
        (__attribute__((address_space(3))) void*)l, 16, 0, 0);
}

__global__ __launch_bounds__(512, 2) void gemm_i8_2ph(
    const char* __restrict__ xq, const char* __restrict__ wq,
    const float* __restrict__ w_scale, const unsigned* __restrict__ amax,
    const float* __restrict__ bias, float* __restrict__ out,
    int M, int N, int K) {
    // LDS: 3 x { A[256][64] , B[512][64] } = 144 KiB
    __shared__ __align__(16) char lds[3 * BUF_SZ];

    // XCD-aware bijective swizzle (nwg = 512, % 8 == 0)
    const int nwg = gridDim.x, bid = blockIdx.x;
    const int cpx = nwg >> 3;
    const int swz = (bid & 7) * cpx + (bid >> 3);
    const int nbm = M / BM;
    const int bm = swz % nbm, bn = swz / nbm;

    const int t = threadIdx.x;
    const int lane = t & 63, wid = t >> 6;
    const int wr = wid >> 2, wc = wid & 3;  // 2 (M) x 4 (N); wave out = 128x128

    // ---- staging: linear LDS dest (t*16), pre-swizzled global source col ----
    // swizzle: col16' = col16 ^ ((row>>1)&3)  (involution, 64B rows)
    const int srow = t >> 2;
    const int scol = ((t & 3) ^ ((srow >> 1) & 3)) << 4;
    const char* aSrc = xq + (size_t)(bm * BM + srow) * K + scol;
    const char* bSrc = wq + (size_t)(bn * BN + srow) * K + scol;
    char* ldsT = lds + t * 16;

    auto stageA = [&](unsigned st, int ktc) {  // 2 loads: rows +0, +128
        char* d = ldsT + st;
        gload16(aSrc + ktc, d);
        gload16(aSrc + (size_t)128 * K + ktc, d + 8192);
    };
    auto stageB = [&](unsigned st, int ktc) {  // 4 loads: rows +0,+128,+256,+384
        char* d = ldsT + st + 16384u;
        gload16(bSrc + ktc, d);
        gload16(bSrc + (size_t)128 * K + ktc, d + 8192);
        gload16(bSrc + (size_t)256 * K + ktc, d + 16384);
        gload16(bSrc + (size_t)384 * K + ktc, d + 24576);
    };

    // ---- ds_read addressing ----
    const int rA = lane & 15, kg = lane >> 4;
    const unsigned cks = (unsigned)((kg ^ ((rA >> 1) & 3)) << 4);
    // a[m]: rd + wr*8192 + (16m+rA)*64 + cks
    const unsigned aB = ((unsigned)wr << 13) + ((unsigned)rA << 6) + cks;
    // b[n]: rd + 16384 + wc*8192 + (16n+rA)*64 + cks
    const unsigned bB = 16384u + ((unsigned)wc << 13) + ((unsigned)rA << 6) + cks;

    v4i acc[8][8];
#pragma unroll
    for (int m = 0; m < 8; m++)
#pragma unroll
        for (int n = 0; n < 8; n++) acc[m][n] = (v4i){0, 0, 0, 0};

    const int nkt = K / BKB;  // 64

    // ---- prologue: stage tiles 0 and 1 ----
    stageA(0, 0); stageB(0, 0);
    {
        const int k1 = (1 < nkt) ? BKB : 0;
        stageA(BUF_SZ, k1); stageB(BUF_SZ, k1);
    }
    asm volatile("s_waitcnt vmcnt(6)" ::: "memory");  // tile0's 6 loads retired
    __builtin_amdgcn_s_barrier();

    unsigned rd = 0, st = 2 * BUF_SZ;
    for (int T = 0; T < nkt; ++T) {
        const int kT2 = (T + 2 < nkt) ? (T + 2) * BKB : 0;  // clamped: always issue
        v4i a[8], b[4];

        // ===== ph1: read a[0..7] + b[0..3] (12); stage A(T+2); MFMA n0-3 =====
#pragma unroll
        for (int m = 0; m < 8; m++)
            a[m] = *(const v4i*)(lds + rd + aB + ((unsigned)m << 10));
#pragma unroll
        for (int n = 0; n < 4; n++)
            b[n] = *(const v4i*)(lds + rd + bB + ((unsigned)n << 10));
        stageA(st, kT2);
        __builtin_amdgcn_s_barrier();
        asm volatile("s_waitcnt lgkmcnt(0)" ::: "memory");
        __builtin_amdgcn_sched_barrier(0);
        __builtin_amdgcn_s_setprio(1);
#pragma unroll
        for (int n = 0; n < 4; n++)
#pragma unroll
            for (int m = 0; m < 8; m++)
                acc[m][n] = __builtin_amdgcn_mfma_i32_16x16x64_i8(a[m], b[n], acc[m][n], 0, 0, 0);
        __builtin_amdgcn_s_setprio(0);
        // no post-MFMA barrier: drift-by-one allowed

        // ===== ph2: read b[4..7] (4); stage B(T+2); vmcnt(6); MFMA n4-7 =====
#pragma unroll
        for (int n = 0; n < 4; n++)
            b[n] = *(const v4i*)(lds + rd + bB + 4096u + ((unsigned)n << 10));
        stageB(st, kT2);
        asm volatile("s_waitcnt vmcnt(6)" ::: "memory");  // retires tile T+1's 6
        __builtin_amdgcn_s_barrier();
        asm volatile("s_waitcnt lgkmcnt(0)" ::: "memory");
        __builtin_amdgcn_sched_barrier(0);
        __builtin_amdgcn_s_setprio(1);
#pragma unroll
        for (int n = 0; n < 4; n++)
#pragma unroll
            for (int m = 0; m < 8; m++)
                acc[m][4 + n] = __builtin_amdgcn_mfma_i32_16x16x64_i8(a[m], b[n], acc[m][4 + n], 0, 0, 0);
        __builtin_amdgcn_s_setprio(0);
        // no post-MFMA barrier

        rd = (rd == 2 * BUF_SZ) ? 0u : rd + BUF_SZ;
        st = (st == 2 * BUF_SZ) ? 0u : st + BUF_SZ;
    }

    // ---- epilogue: y = acc * (a_scale * w_scale[col]) + bias[col] ----
    float a_s = fmaxf(__uint_as_float(*amax) / QMAX_F, EPS_F);
    const int row0 = bm * BM + wr * 128 + (kg << 2);
    const int col0 = bn * BN + wc * 128 + rA;
#pragma unroll
    for (int n = 0; n < 8; n++) {
        int col = col0 + n * 16;
        float f = a_s * w_scale[col];
        float bv = bias[col];
#pragma unroll
        for (int m = 0; m < 8; m++) {
            size_t base = (size_t)(row0 + m * 16) * N + col;
#pragma unroll
            for (int j = 0; j < 4; j++)
                out[base + (size_t)j * N] = (float)acc[m][n][j] * f + bv;
        }
    }
}

extern "C" void kernel_launch(void* const* d_in, const int* in_sizes, int n_in,
                              void* d_out, int out_size, void* d_ws, size_t ws_size,
                              hipStream_t stream) {
    const float* x = (const float*)d_in[0];
    const float* w = (const float*)d_in[1];
    const float* bias = (const float*)d_in[2];
    float* out = (float*)d_out;

    const int N = in_sizes[2];      // 4096
    const int K = in_sizes[1] / N;  // 4096
    const int M = in_sizes[0] / K;  // 16384

    char* ws = (char*)d_ws;
    unsigned* amax = (unsigned*)ws;
    float* w_scale = (float*)(ws + WSCALE_OFF);
    char* xq = ws + XQ_OFF;
    char* wq = ws + XQ_OFF + (size_t)M * K;

    size_t needed = XQ_OFF + (size_t)M * K + (size_t)N * K;
    if (ws_size < needed) return;

    hipMemsetAsync(amax, 0, 4, stream);

    int n4x = (M * K) / 4;
    prep_kernel<<<N, 256, 0, stream>>>((const float4*)x, n4x, (const float4*)w,
                                       (int*)wq, w_scale, K / 4, amax);
    quantx_kernel<<<2048, 256, 0, stream>>>((const float4*)x, amax, (int*)xq, n4x);

    int grid = (M / BM) * (N / BN);  // 64*8 = 512
    gemm_i8_2ph<<<grid, 512, 0, stream>>>(xq, wq, w_scale, amax, bias, out, M, N, K);
}

// Round 7
// 527.668 us; speedup vs baseline: 3.3547x; 3.3547x over previous
//
#include <hip/hip_runtime.h>
#include <hip/hip_bf16.h>
#include <stdint.h>

// ---------------------------------------------------------------------------
// LinearQuantizer: y = fakequant_i8(x, per-tensor) @ fakequant_i8(W, per-row)^T + b
// int8 GEMM via v_mfma_i32_16x16x64_i8. 256x256 tile, BK=64, 4 LDS buffers,
// 256 threads (4 waves, 1 wave/SIMD, 512-reg budget), per-wave 128x128
// (acc[8][8] in AGPRs), register-double-buffered fragments, 1 barrier/K-step,
// counted vmcnt(16), lgkmcnt(0)-before-barrier for formal race-freedom.
// ---------------------------------------------------------------------------

#define QMAX_F 127.0f
#define EPS_F 1e-8f

typedef int v4i __attribute__((ext_vector_type(4)));

static constexpr size_t WSCALE_OFF = 64;
static constexpr size_t XQ_OFF = 1u << 16;

__device__ __forceinline__ int quant1m(float v, float rs) {
    float t = v * rs;
    t = fminf(fmaxf(t, -QMAX_F), QMAX_F);
    return (int)rintf(t);
}

// ---------------- prep: x-absmax (atomicMax) + per-row W quant ----------------
__global__ void prep_kernel(const float4* __restrict__ x, int nx4,
                            const float4* __restrict__ w, int* __restrict__ wq,
                            float* __restrict__ w_scale, int K4,
                            unsigned* __restrict__ amax) {
    const int t = threadIdx.x;  // 256
    const int row = blockIdx.x;

    float xm = 0.0f;
    for (int i = blockIdx.x * 256 + t; i < nx4; i += gridDim.x * 256) {
        float4 v = x[i];
        xm = fmaxf(xm, fmaxf(fmaxf(fabsf(v.x), fabsf(v.y)), fmaxf(fabsf(v.z), fabsf(v.w))));
    }

    const float4* wr = w + (size_t)row * K4;
    float4 vals[4];
    float wm = 0.0f;
    for (int i = 0; i < 4; i++) {
        float4 v = wr[t + 256 * i];
        vals[i] = v;
        wm = fmaxf(wm, fmaxf(fmaxf(fabsf(v.x), fabsf(v.y)), fmaxf(fabsf(v.z), fabsf(v.w))));
    }

    for (int off = 32; off > 0; off >>= 1) {
        xm = fmaxf(xm, __shfl_xor(xm, off));
        wm = fmaxf(wm, __shfl_xor(wm, off));
    }
    __shared__ float sx[4], sw[4];
    if ((t & 63) == 0) { sx[t >> 6] = xm; sw[t >> 6] = wm; }
    __syncthreads();
    float xb = fmaxf(fmaxf(sx[0], sx[1]), fmaxf(sx[2], sx[3]));
    float wb = fmaxf(fmaxf(sw[0], sw[1]), fmaxf(sw[2], sw[3]));
    if (t == 0) atomicMax(amax, __float_as_uint(xb));

    float s = fmaxf(wb / QMAX_F, EPS_F);
    if (t == 0) w_scale[row] = s;
    float rs = 1.0f / s;
    int* wqr = wq + (size_t)row * K4;
    for (int i = 0; i < 4; i++) {
        float4 v = vals[i];
        int q0 = quant1m(v.x, rs), q1 = quant1m(v.y, rs), q2 = quant1m(v.z, rs), q3 = quant1m(v.w, rs);
        wqr[t + 256 * i] = (q0 & 0xff) | ((q1 & 0xff) << 8) | ((q2 & 0xff) << 16) | ((q3 & 0xff) << 24);
    }
}

// ---------------- quantize x -> int8 ----------------
__global__ void quantx_kernel(const float4* __restrict__ x, const unsigned* __restrict__ amax,
                              int* __restrict__ xq, int n4) {
    float s = fmaxf(__uint_as_float(*amax) / QMAX_F, EPS_F);
    float rs = 1.0f / s;
    int tid = blockIdx.x * blockDim.x + threadIdx.x;
    int stride = gridDim.x * blockDim.x;
    for (int i = tid; i < n4; i += stride) {
        float4 v = x[i];
        int q0 = quant1m(v.x, rs), q1 = quant1m(v.y, rs), q2 = quant1m(v.z, rs), q3 = quant1m(v.w, rs);
        xq[i] = (q0 & 0xff) | ((q1 & 0xff) << 8) | ((q2 & 0xff) << 16) | ((q3 & 0xff) << 24);
    }
}

// ---------------- int8 GEMM: 256x256 tile, BK=64, 4 bufs, 4 waves ----------
#define BM 256
#define BN 256
#define BKB 64

__device__ __forceinline__ void gload16(const char* g, char* l) {
    __builtin_amdgcn_global_load_lds(
        (const __attribute__((address_space(1))) void*)g,
        (__attribute__((address_space(3))) void*)l, 16, 0, 0);
}

__global__ __launch_bounds__(256, 1) void gemm_i8_big(
    const char* __restrict__ xq, const char* __restrict__ wq,
    const float* __restrict__ w_scale, const unsigned* __restrict__ amax,
    const float* __restrict__ bias, float* __restrict__ out,
    int M, int N, int K) {
    // LDS: 4 bufs x { A[256][64] 16KB + B[256][64] 16KB } = 128 KiB
    __shared__ __align__(16) char lds[131072];

    // XCD-aware bijective swizzle (nwg = 1024, % 8 == 0)
    const int nwg = gridDim.x, bid = blockIdx.x;
    const int cpx = nwg >> 3;
    const int swz = (bid & 7) * cpx + (bid >> 3);
    const int nbm = M / BM;
    const int bm = swz % nbm, bn = swz / nbm;

    const int t = threadIdx.x;
    const int lane = t & 63, wid = t >> 6;
    const int wr = wid >> 1, wc = wid & 1;  // 2x2 waves; wave out = 128x128

    // ---- staging: linear LDS dest (t*16), pre-swizzled global source col ----
    // swizzle: col16' = col16 ^ ((row>>1)&3)  (involution on 64B rows)
    const int srow = t >> 2;
    const int scol = ((t & 3) ^ ((srow >> 1) & 3)) << 4;
    const char* aSrc = xq + (size_t)(bm * BM + srow) * K + scol;
    const char* bSrc = wq + (size_t)(bn * BN + srow) * K + scol;
    char* ldsT = lds + t * 16;

    auto stage = [&](unsigned bufOff, int ktc) {  // 8 gloads: A 16KB + B 16KB
        char* d = ldsT + bufOff;
#pragma unroll
        for (int i = 0; i < 4; i++)
            gload16(aSrc + (size_t)(i * 64) * K + ktc, d + i * 4096);
#pragma unroll
        for (int i = 0; i < 4; i++)
            gload16(bSrc + (size_t)(i * 64) * K + ktc, d + 16384 + i * 4096);
    };

    // ---- ds_read addressing (same conflict-free pattern as r6: 0 conflicts) ----
    const int rA = lane & 15, kg = lane >> 4;
    const unsigned cks = (unsigned)((kg ^ ((rA >> 1) & 3)) << 4);
    const unsigned aB = ((unsigned)wr << 13) + ((unsigned)rA << 6) + cks;
    const unsigned bB = 16384u + ((unsigned)wc << 13) + ((unsigned)rA << 6) + cks;

    v4i f0[16], f1[16];  // frag sets: [0..7]=A, [8..15]=B
    v4i acc[8][8];
#pragma unroll
    for (int m = 0; m < 8; m++)
#pragma unroll
        for (int n = 0; n < 8; n++) acc[m][n] = (v4i){0, 0, 0, 0};

    auto ldfrags = [&](v4i(&f)[16], unsigned bufOff) {
#pragma unroll
        for (int m = 0; m < 8; m++)
            f[m] = *(const v4i*)(lds + bufOff + aB + ((unsigned)m << 10));
#pragma unroll
        for (int n = 0; n < 8; n++)
            f[8 + n] = *(const v4i*)(lds + bufOff + bB + ((unsigned)n << 10));
    };

    auto mfma64 = [&](v4i(&f)[16]) {
#pragma unroll
        for (int n = 0; n < 8; n++)
#pragma unroll
            for (int m = 0; m < 8; m++)
                acc[m][n] = __builtin_amdgcn_mfma_i32_16x16x64_i8(f[m], f[8 + n], acc[m][n], 0, 0, 0);
    };

    const int nkt = K / BKB;  // 64 (multiple of 4)

    // ---- prologue: stage tiles 0,1,2; load frags(0) ----
    stage(0u, 0);
    stage(32768u, BKB);
    stage(65536u, 2 * BKB);
    asm volatile("s_waitcnt vmcnt(16)" ::: "memory");  // tile0 resident
    __builtin_amdgcn_s_barrier();
    ldfrags(f0, 0u);

    // steady state per step: stage(T+3); vmcnt(16); lgkm(0); barrier;
    // ds_read frags(T+1) (other set); 64 MFMA on current set.
    for (int T = 0; T < nkt; T += 4) {
        {  // u=0: compute f0=frags(T); read f1<-buf1; stage buf3 (tile T+3)
            int ks = (T + 3 < nkt) ? (T + 3) * BKB : 0;
            stage(98304u, ks);
            asm volatile("s_waitcnt vmcnt(16)" ::: "memory");
            asm volatile("s_waitcnt lgkmcnt(0)" ::: "memory");
            __builtin_amdgcn_s_barrier();
            ldfrags(f1, 32768u);
            mfma64(f0);
        }
        {  // u=1: compute f1=frags(T+1); read f0<-buf2; stage buf0 (tile T+4)
            int ks = (T + 4 < nkt) ? (T + 4) * BKB : 0;
            stage(0u, ks);
            asm volatile("s_waitcnt vmcnt(16)" ::: "memory");
            asm volatile("s_waitcnt lgkmcnt(0)" ::: "memory");
            __builtin_amdgcn_s_barrier();
            ldfrags(f0, 65536u);
            mfma64(f1);
        }
        {  // u=2: compute f0=frags(T+2); read f1<-buf3; stage buf1 (tile T+5)
            int ks = (T + 5 < nkt) ? (T + 5) * BKB : 0;
            stage(32768u, ks);
            asm volatile("s_waitcnt vmcnt(16)" ::: "memory");
            asm volatile("s_waitcnt lgkmcnt(0)" ::: "memory");
            __builtin_amdgcn_s_barrier();
            ldfrags(f1, 98304u);
            mfma64(f0);
        }
        {  // u=3: compute f1=frags(T+3); read f0<-buf0; stage buf2 (tile T+6)
            int ks = (T + 6 < nkt) ? (T + 6) * BKB : 0;
            stage(65536u, ks);
            asm volatile("s_waitcnt vmcnt(16)" ::: "memory");
            asm volatile("s_waitcnt lgkmcnt(0)" ::: "memory");
            __builtin_amdgcn_s_barrier();
            ldfrags(f0, 0u);
            mfma64(f1);
        }
    }

    // ---- epilogue: y = acc * (a_scale * w_scale[col]) + bias[col] ----
    float a_s = fmaxf(__uint_as_float(*amax) / QMAX_F, EPS_F);
    const int row0 = bm * BM + wr * 128 + (kg << 2);
    const int col0 = bn * BN + wc * 128 + rA;
#pragma unroll
    for (int n = 0; n < 8; n++) {
        int col = col0 + n * 16;
        float f = a_s * w_scale[col];
        float bv = bias[col];
#pragma unroll
        for (int m = 0; m < 8; m++) {
            size_t base = (size_t)(row0 + m * 16) * N + col;
#pragma unroll
            for (int j = 0; j < 4; j++)
                out[base + (size_t)j * N] = (float)acc[m][n][j] * f + bv;
        }
    }
}

extern "C" void kernel_launch(void* const* d_in, const int* in_sizes, int n_in,
                              void* d_out, int out_size, void* d_ws, size_t ws_size,
                              hipStream_t stream) {
    const float* x = (const float*)d_in[0];
    const float* w = (const float*)d_in[1];
    const float* bias = (const float*)d_in[2];
    float* out = (float*)d_out;

    const int N = in_sizes[2];      // 4096
    const int K = in_sizes[1] / N;  // 4096
    const int M = in_sizes[0] / K;  // 16384

    char* ws = (char*)d_ws;
    unsigned* amax = (unsigned*)ws;
    float* w_scale = (float*)(ws + WSCALE_OFF);
    char* xq = ws + XQ_OFF;
    char* wq = ws + XQ_OFF + (size_t)M * K;

    size_t needed = XQ_OFF + (size_t)M * K + (size_t)N * K;
    if (ws_size < needed) return;

    hipMemsetAsync(amax, 0, 4, stream);

    int n4x = (M * K) / 4;
    prep_kernel<<<N, 256, 0, stream>>>((const float4*)x, n4x, (const float4*)w,
                                       (int*)wq, w_scale, K / 4, amax);
    quantx_kernel<<<2048, 256, 0, stream>>>((const float4*)x, amax, (int*)xq, n4x);

    int grid = (M / BM) * (N / BN);  // 64*16 = 1024
    gemm_i8_big<<<grid, 256, 0, stream>>>(xq, wq, w_scale, amax, bias, out, M, N, K);
}

// Round 8
// 431.497 us; speedup vs baseline: 4.1024x; 1.2229x over previous
//
#include <hip/hip_runtime.h>
#include <hip/hip_bf16.h>
#include <stdint.h>

// ---------------------------------------------------------------------------
// LinearQuantizer: y = fakequant_i8(x, per-tensor) @ fakequant_i8(W, per-row)^T + b
// int8 GEMM via v_mfma_i32_16x16x64_i8, 256x256 tile, 8 waves, 4-phase
// schedule with counted vmcnt + T2 swizzle + T5 setprio + drift-by-one
// (r4 champion) with ph2's barrier removed (3 barriers/K-tile).
// prep kernel fuses x-absmax + W quant (r5).
// ---------------------------------------------------------------------------

#define QMAX_F 127.0f
#define EPS_F 1e-8f

typedef int v4i __attribute__((ext_vector_type(4)));

static constexpr size_t WSCALE_OFF = 64;
static constexpr size_t XQ_OFF = 1u << 16;

__device__ __forceinline__ int quant1m(float v, float rs) {
    float t = v * rs;
    t = fminf(fmaxf(t, -QMAX_F), QMAX_F);
    return (int)rintf(t);
}

// ---------------- prep: x-absmax (atomicMax) + per-row W quant ----------------
__global__ void prep_kernel(const float4* __restrict__ x, int nx4,
                            const float4* __restrict__ w, int* __restrict__ wq,
                            float* __restrict__ w_scale, int K4,
                            unsigned* __restrict__ amax) {
    const int t = threadIdx.x;  // 256
    const int row = blockIdx.x;

    float xm = 0.0f;
    for (int i = blockIdx.x * 256 + t; i < nx4; i += gridDim.x * 256) {
        float4 v = x[i];
        xm = fmaxf(xm, fmaxf(fmaxf(fabsf(v.x), fabsf(v.y)), fmaxf(fabsf(v.z), fabsf(v.w))));
    }

    const float4* wr = w + (size_t)row * K4;
    float4 vals[4];
    float wm = 0.0f;
    for (int i = 0; i < 4; i++) {
        float4 v = wr[t + 256 * i];
        vals[i] = v;
        wm = fmaxf(wm, fmaxf(fmaxf(fabsf(v.x), fabsf(v.y)), fmaxf(fabsf(v.z), fabsf(v.w))));
    }

    for (int off = 32; off > 0; off >>= 1) {
        xm = fmaxf(xm, __shfl_xor(xm, off));
        wm = fmaxf(wm, __shfl_xor(wm, off));
    }
    __shared__ float sx[4], sw[4];
    if ((t & 63) == 0) { sx[t >> 6] = xm; sw[t >> 6] = wm; }
    __syncthreads();
    float xb = fmaxf(fmaxf(sx[0], sx[1]), fmaxf(sx[2], sx[3]));
    float wb = fmaxf(fmaxf(sw[0], sw[1]), fmaxf(sw[2], sw[3]));
    if (t == 0) atomicMax(amax, __float_as_uint(xb));

    float s = fmaxf(wb / QMAX_F, EPS_F);
    if (t == 0) w_scale[row] = s;
    float rs = 1.0f / s;
    int* wqr = wq + (size_t)row * K4;
    for (int i = 0; i < 4; i++) {
        float4 v = vals[i];
        int q0 = quant1m(v.x, rs), q1 = quant1m(v.y, rs), q2 = quant1m(v.z, rs), q3 = quant1m(v.w, rs);
        wqr[t + 256 * i] = (q0 & 0xff) | ((q1 & 0xff) << 8) | ((q2 & 0xff) << 16) | ((q3 & 0xff) << 24);
    }
}

// ---------------- quantize x -> int8 ----------------
__global__ void quantx_kernel(const float4* __restrict__ x, const unsigned* __restrict__ amax,
                              int* __restrict__ xq, int n4) {
    float s = fmaxf(__uint_as_float(*amax) / QMAX_F, EPS_F);
    float rs = 1.0f / s;
    int tid = blockIdx.x * blockDim.x + threadIdx.x;
    int stride = gridDim.x * blockDim.x;
    for (int i = tid; i < n4; i += stride) {
        float4 v = x[i];
        int q0 = quant1m(v.x, rs), q1 = quant1m(v.y, rs), q2 = quant1m(v.z, rs), q3 = quant1m(v.w, rs);
        xq[i] = (q0 & 0xff) | ((q1 & 0xff) << 8) | ((q2 & 0xff) << 16) | ((q3 & 0xff) << 24);
    }
}

// ---------------- int8 GEMM, 256x256 tile, 3-barrier 4-phase ----------
#define BM 256
#define BN 256
#define BKB 128  // K-bytes (=elements) per K-tile

__device__ __forceinline__ void gload16(const char* g, char* l) {
    __builtin_amdgcn_global_load_lds(
        (const __attribute__((address_space(1))) void*)g,
        (__attribute__((address_space(3))) void*)l, 16, 0, 0);
}

__global__ __launch_bounds__(512, 2) void gemm_i8_8ph(
    const char* __restrict__ xq, const char* __restrict__ wq,
    const float* __restrict__ w_scale, const unsigned* __restrict__ amax,
    const float* __restrict__ bias, float* __restrict__ out,
    int M, int N, int K) {
    // LDS: [buf 2][op 2 (A,B)][half 2][row 128][col 128B] = 128 KiB
    __shared__ __align__(16) char lds[131072];

    // XCD-aware bijective swizzle (nwg = 1024, % 8 == 0)
    const int nwg = gridDim.x, bid = blockIdx.x;
    const int cpx = nwg >> 3;
    const int swz = (bid & 7) * cpx + (bid >> 3);
    const int nbm = M / BM;
    const int bm = swz % nbm, bn = swz / nbm;

    const int t = threadIdx.x;
    const int lane = t & 63, wid = t >> 6;
    const int wr = wid >> 2, wc = wid & 3;  // 2 (M) x 4 (N) waves; wave out = 128x64

    // ---- staging: linear LDS dest (t*16), pre-swizzled global source col ----
    const int srow = t >> 3;
    const int scol = ((t & 7) ^ (srow & 7)) << 4;
    const char* aSrc = xq + (size_t)(bm * BM + srow) * K + scol;
    const char* bSrc = wq + (size_t)(bn * BN + srow) * K + scol;
    char* ldsT = lds + t * 16;

    auto stageA = [&](int half, int tt, int ktc) {
        char* d = ldsT + ((unsigned)(tt & 1) << 16) + ((unsigned)half << 14);
        gload16(aSrc + (size_t)(half * 128) * K + ktc, d);
        gload16(aSrc + (size_t)(half * 128 + 64) * K + ktc, d + 8192);
    };
    auto stageB = [&](int half, int tt, int ktc) {
        char* d = ldsT + ((unsigned)(tt & 1) << 16) + 32768u + ((unsigned)half << 14);
        gload16(bSrc + (size_t)(half * 128) * K + ktc, d);
        gload16(bSrc + (size_t)(half * 128 + 64) * K + ktc, d + 8192);
    };

    // ---- ds_read addressing (swizzled col: byte ^= ((row&7)<<4)) ----
    const int rA = lane & 15, kg = lane >> 4, sw7 = lane & 7;
    const unsigned cks0 = (unsigned)((kg ^ sw7) << 4);
    const unsigned cks1 = (unsigned)(((4 + kg) ^ sw7) << 4);
    const unsigned aBase = ((unsigned)wr << 14) + ((unsigned)rA << 7);
    const unsigned bBase = 32768u + ((unsigned)wc << 13) + ((unsigned)rA << 7);

    v4i acc[8][4];
#pragma unroll
    for (int m = 0; m < 8; m++)
#pragma unroll
        for (int n = 0; n < 4; n++) acc[m][n] = (v4i){0, 0, 0, 0};

    const int nkt = K / BKB;  // 32

    // ---- prologue: tile0 fully + 3 half-tiles of tile1 ----
    stageA(0, 0, 0); stageA(1, 0, 0); stageB(0, 0, 0); stageB(1, 0, 0);
    {
        const int k1 = (1 < nkt) ? BKB : 0;
        stageB(0, 1, k1); stageA(0, 1, k1); stageB(1, 1, k1);
    }
    asm volatile("s_waitcnt vmcnt(6)" ::: "memory");  // tile0's 8 loads retired
    __builtin_amdgcn_s_barrier();

    for (int T = 0; T < nkt; ++T) {
        const unsigned bb = (unsigned)(T & 1) << 16;
        const int kA1 = (T + 1 < nkt) ? (T + 1) * BKB : 0;  // clamped: loads always issue
        const int kT2 = (T + 2 < nkt) ? (T + 2) * BKB : 0;
        v4i a[4][2], b0[2][2], b1[2][2];

        // ===== ph1: read A-mh0 (8) + B-nh0 (4); stage A-h1(T+1); MFMA q(0,0) =====
#pragma unroll
        for (int m = 0; m < 4; m++) {
            a[m][0] = *(const v4i*)(lds + bb + aBase + ((unsigned)m << 11) + cks0);
            a[m][1] = *(const v4i*)(lds + bb + aBase + ((unsigned)m << 11) + cks1);
        }
#pragma unroll
        for (int n = 0; n < 2; n++) {
            b0[n][0] = *(const v4i*)(lds + bb + bBase + ((unsigned)n << 11) + cks0);
            b0[n][1] = *(const v4i*)(lds + bb + bBase + ((unsigned)n << 11) + cks1);
        }
        stageA(1, T + 1, kA1);
        __builtin_amdgcn_s_barrier();
        asm volatile("s_waitcnt lgkmcnt(0)" ::: "memory");
        __builtin_amdgcn_sched_barrier(0);
        __builtin_amdgcn_s_setprio(1);
#pragma unroll
        for (int ks = 0; ks < 2; ks++)
#pragma unroll
            for (int m = 0; m < 4; m++)
#pragma unroll
                for (int n = 0; n < 2; n++)
                    acc[m][n] = __builtin_amdgcn_mfma_i32_16x16x64_i8(a[m][ks], b0[n][ks], acc[m][n], 0, 0, 0);
        __builtin_amdgcn_s_setprio(0);
        // (no post-MFMA barrier: waves may drift into ph2)

        // ===== ph2: read B-nh1 (4); lgkm only (NO barrier); MFMA q(0,1) =====
        // Safety: writers of bb (ph4 stages) only issue after ph3's barrier;
        // any wave's ph2 reads are issued before it reaches ph3's barrier and
        // drain in ~200cyc, while a global_load_lds write lands >=~900cyc
        // after that same barrier event -> ordered by timing margin (same
        // argument as r4's ph3/ph4 soft-race, 50+ exact-match replays).
#pragma unroll
        for (int n = 0; n < 2; n++) {
            b1[n][0] = *(const v4i*)(lds + bb + bBase + 4096u + ((unsigned)n << 11) + cks0);
            b1[n][1] = *(const v4i*)(lds + bb + bBase + 4096u + ((unsigned)n << 11) + cks1);
        }
        asm volatile("s_waitcnt lgkmcnt(0)" ::: "memory");
        __builtin_amdgcn_sched_barrier(0);
        __builtin_amdgcn_s_setprio(1);
#pragma unroll
        for (int ks = 0; ks < 2; ks++)
#pragma unroll
            for (int m = 0; m < 4; m++)
#pragma unroll
                for (int n = 0; n < 2; n++)
                    acc[m][2 + n] = __builtin_amdgcn_mfma_i32_16x16x64_i8(a[m][ks], b1[n][ks], acc[m][2 + n], 0, 0, 0);
        __builtin_amdgcn_s_setprio(0);

        // ===== ph3: read A-mh1 (8); MFMA q(1,1) =====
#pragma unroll
        for (int m = 0; m < 4; m++) {
            a[m][0] = *(const v4i*)(lds + bb + aBase + 8192u + ((unsigned)m << 11) + cks0);
            a[m][1] = *(const v4i*)(lds + bb + aBase + 8192u + ((unsigned)m << 11) + cks1);
        }
        __builtin_amdgcn_s_barrier();
        asm volatile("s_waitcnt lgkmcnt(0)" ::: "memory");
        __builtin_amdgcn_sched_barrier(0);
        __builtin_amdgcn_s_setprio(1);
#pragma unroll
        for (int ks = 0; ks < 2; ks++)
#pragma unroll
            for (int m = 0; m < 4; m++)
#pragma unroll
                for (int n = 0; n < 2; n++)
                    acc[4 + m][2 + n] = __builtin_amdgcn_mfma_i32_16x16x64_i8(a[m][ks], b1[n][ks], acc[4 + m][2 + n], 0, 0, 0);
        __builtin_amdgcn_s_setprio(0);

        // ===== ph4: stage B-h0+A-h0+B-h1(T+2); vmcnt(6); MFMA q(1,0) =====
        stageB(0, T + 2, kT2);
        stageA(0, T + 2, kT2);
        stageB(1, T + 2, kT2);
        asm volatile("s_waitcnt vmcnt(6)" ::: "memory");  // retires all of tile T+1
        __builtin_amdgcn_s_barrier();
        __builtin_amdgcn_s_setprio(1);
#pragma unroll
        for (int ks = 0; ks < 2; ks++)
#pragma unroll
            for (int m = 0; m < 4; m++)
#pragma unroll
                for (int n = 0; n < 2; n++)
                    acc[4 + m][n] = __builtin_amdgcn_mfma_i32_16x16x64_i8(a[m][ks], b0[n][ks], acc[4 + m][n], 0, 0, 0);
        __builtin_amdgcn_s_setprio(0);
        // (no post-MFMA barrier)
    }

    // ---- epilogue: y = acc * (a_scale * w_scale[col]) + bias[col] ----
    float a_s = fmaxf(__uint_as_float(*amax) / QMAX_F, EPS_F);
    const int row0 = bm * BM + wr * 128;
    const int col0 = bn * BN + wc * 64;
#pragma unroll
    for (int n = 0; n < 4; n++) {
        int col = col0 + n * 16 + rA;
        float f = a_s * w_scale[col];
        float bv = bias[col];
#pragma unroll
        for (int m = 0; m < 8; m++) {
            int row = row0 + m * 16 + (kg << 2);
            size_t base = (size_t)row * N + col;
#pragma unroll
            for (int j = 0; j < 4; j++)
                out[base + (size_t)j * N] = (float)acc[m][n][j] * f + bv;
        }
    }
}

extern "C" void kernel_launch(void* const* d_in, const int* in_sizes, int n_in,
                              void* d_out, int out_size, void* d_ws, size_t ws_size,
                              hipStream_t stream) {
    const float* x = (const float*)d_in[0];
    const float* w = (const float*)d_in[1];
    const float* bias = (const float*)d_in[2];
    float* out = (float*)d_out;

    const int N = in_sizes[2];      // 4096
    const int K = in_sizes[1] / N;  // 4096
    const int M = in_sizes[0] / K;  // 16384

    char* ws = (char*)d_ws;
    unsigned* amax = (unsigned*)ws;
    float* w_scale = (float*)(ws + WSCALE_OFF);
    char* xq = ws + XQ_OFF;
    char* wq = ws + XQ_OFF + (size_t)M * K;

    size_t needed = XQ_OFF + (size_t)M * K + (size_t)N * K;
    if (ws_size < needed) return;

    hipMemsetAsync(amax, 0, 4, stream);

    int n4x = (M * K) / 4;
    prep_kernel<<<N, 256, 0, stream>>>((const float4*)x, n4x, (const float4*)w,
                                       (int*)wq, w_scale, K / 4, amax);
    quantx_kernel<<<2048, 256, 0, stream>>>((const float4*)x, amax, (int*)xq, n4x);

    int grid = (M / BM) * (N / BN);  // 64*16 = 1024
    gemm_i8_8ph<<<grid, 512, 0, stream>>>(xq, wq, w_scale, amax, bias, out, M, N, K);
}